// Round 1
// baseline (537.017 us; speedup 1.0000x reference)
//
#include <hip/hip_runtime.h>

#define MM 128
#define NN 128
#define KK 128
#define NBATCH 4
#define ITERS 8
#define WIN 10
#define WSTRIDE 12
#define MNK (MM*NN*KK)

__device__ __forceinline__ float wave_sum(float v) {
  v += __shfl_xor(v, 32, 64);
  v += __shfl_xor(v, 16, 64);
  v += __shfl_xor(v, 8, 64);
  v += __shfl_xor(v, 4, 64);
  v += __shfl_xor(v, 2, 64);
  v += __shfl_xor(v, 1, 64);
  return v;
}

// One workgroup per spatial 8^3 block (4096 blocks). 128 threads:
// thread t -> p = t>>4 (0..7), q0 = 2*((t>>2)&3), r0 = 2*(t&3); each thread
// owns a (1,2,2) micro-tile of interior positions for ALL 4 batches, with the
// 27*4 conv weights held in registers across batches+iterations.
__global__ __launch_bounds__(128, 2) void gridnet_kernel(
    const float* __restrict__ weight, const float* __restrict__ bias,
    const float* __restrict__ rscale, const float* __restrict__ x,
    float* __restrict__ out) {
  // window rows padded 10 -> 12 floats: float2-aligned and 2-way-bank-free
  __shared__ __align__(16) float Wl[WIN * WIN * WSTRIDE];
  __shared__ float red[8];

  const int t = threadIdx.x;
  const int r2 = t & 3, q2 = (t >> 2) & 3, p = t >> 4;
  const int r0 = r2 * 2, q0 = q2 * 2;
  const int bx = blockIdx.x;
  const int bm = bx >> 8, bn = (bx >> 4) & 15, bk = bx & 15;

  const int gm0 = bm * 8, gn0 = bn * 8, gk0 = bk * 8;
  const int baseg = ((gm0 + p) * NN + (gn0 + q0)) * KK + (gk0 + r0);

  // per-thread weights: w[dq][dr][o], o = i*9 + j*3 + k
  float w[2][2][27];
  float S[2][2] = {{0.f, 0.f}, {0.f, 0.f}};
#pragma unroll
  for (int dq = 0; dq < 2; ++dq) {
#pragma unroll
    for (int o = 0; o < 27; ++o) {
      float2 wv = *(const float2*)(weight + o * MNK + baseg + dq * KK);
      w[dq][0][o] = wv.x; w[dq][1][o] = wv.y;
      S[dq][0] += wv.x;   S[dq][1] += wv.y;
    }
  }
  float bia[2][2], rsc[2][2];
#pragma unroll
  for (int dq = 0; dq < 2; ++dq) {
    float2 bv = *(const float2*)(bias + baseg + dq * KK);
    bia[dq][0] = bv.x; bia[dq][1] = bv.y;
    float2 rv = *(const float2*)(rscale + baseg + dq * KK);
    rsc[dq][0] = rv.x; rsc[dq][1] = rv.y;
  }

  for (int b = 0; b < NBATCH; ++b) {
    __syncthreads();  // protect Wl from previous batch's readers
    // ---- load 10^3 window (zero-padded at grid boundary) into LDS ----
    float sA = 0.f, sAq = 0.f, sH = 0.f, sHq = 0.f;
    for (int idx = t; idx < 1000; idx += 128) {
      int wp = idx / 100;
      int rem = idx - wp * 100;
      int wq = rem / 10;
      int wk = rem - wq * 10;
      int gm = gm0 - 1 + wp, gn = gn0 - 1 + wq, gk = gk0 - 1 + wk;
      float v = 0.0f;
      if ((unsigned)gm < 128u && (unsigned)gn < 128u && (unsigned)gk < 128u)
        v = x[((b * MM + gm) * NN + gn) * KK + gk];
      Wl[(wp * WIN + wq) * WSTRIDE + wk] = v;
      sA += v; sAq += v * v;
      // halo (window shell) never changes across iterations: fold once
      if (wp == 0 || wp == 9 || wq == 0 || wq == 9 || wk == 0 || wk == 9) {
        sH += v; sHq += v * v;
      }
    }
    sA = wave_sum(sA); sAq = wave_sum(sAq);
    sH = wave_sum(sH); sHq = wave_sum(sHq);
    if ((t & 63) == 0) {
      int wv_ = t >> 6;
      red[wv_ * 4 + 0] = sA; red[wv_ * 4 + 1] = sAq;
      red[wv_ * 4 + 2] = sH; red[wv_ * 4 + 3] = sHq;
    }
    __syncthreads();
    float totS = red[0] + red[4], totQ = red[1] + red[5];
    const float hS = red[2] + red[6], hQ = red[3] + red[7];

    // own interior acts in registers (kept in sync with LDS)
    float a[2][2];
#pragma unroll
    for (int dq = 0; dq < 2; ++dq)
#pragma unroll
      for (int dr = 0; dr < 2; ++dr)
        a[dq][dr] = Wl[((p + 1) * WIN + (q0 + dq + 1)) * WSTRIDE + (r0 + dr + 1)];

    float mu = totS * (1.0f / 1000.0f);
    float var = totQ * (1.0f / 1000.0f) - mu * mu;
    float inv = __builtin_amdgcn_rsqf(var + 1e-5f);

    for (int it = 0; it < ITERS; ++it) {
      // ---- locally-connected 3^3 conv on RAW acts (normalization folded) ----
      float acc[2][2] = {{0.f, 0.f}, {0.f, 0.f}};
#pragma unroll
      for (int i = 0; i < 3; ++i) {
        float v[4][4];
#pragma unroll
        for (int jj = 0; jj < 4; ++jj) {
          const float* bp = &Wl[((p + i) * WIN + (q0 + jj)) * WSTRIDE + r0];
          float2 u0 = *(const float2*)bp;
          float2 u1 = *(const float2*)(bp + 2);
          v[jj][0] = u0.x; v[jj][1] = u0.y; v[jj][2] = u1.x; v[jj][3] = u1.y;
        }
#pragma unroll
        for (int j = 0; j < 3; ++j)
#pragma unroll
          for (int kc = 0; kc < 3; ++kc) {
            const int o = i * 9 + j * 3 + kc;
#pragma unroll
            for (int dq = 0; dq < 2; ++dq) {
              acc[dq][0] += w[dq][0][o] * v[dq + j][kc];
              acc[dq][1] += w[dq][1][o] * v[dq + j][kc + 1];
            }
          }
      }
      // acc_final = bias + inv*(conv_raw) - inv*mu*(sum of 27 weights)
      const float im = inv * mu;
#pragma unroll
      for (int dq = 0; dq < 2; ++dq)
#pragma unroll
        for (int dr = 0; dr < 2; ++dr) {
          float z = bia[dq][dr] + inv * acc[dq][dr] - im * S[dq][dr];
          float e = __expf(-z);
          float sg = __builtin_amdgcn_rcpf(1.0f + e);  // sigmoid(z)
          a[dq][dr] += rsc[dq][dr] * (z * sg);          // residual silu
        }
      if (it < ITERS - 1) {
        __syncthreads();  // all conv reads done before anyone writes
#pragma unroll
        for (int dq = 0; dq < 2; ++dq)
#pragma unroll
          for (int dr = 0; dr < 2; ++dr)
            Wl[((p + 1) * WIN + (q0 + dq + 1)) * WSTRIDE + (r0 + dr + 1)] = a[dq][dr];
        float ls = a[0][0] + a[0][1] + a[1][0] + a[1][1];
        float lq = a[0][0] * a[0][0] + a[0][1] * a[0][1] +
                   a[1][0] * a[1][0] + a[1][1] * a[1][1];
        ls = wave_sum(ls); lq = wave_sum(lq);
        if ((t & 63) == 0) { red[(t >> 6) * 2 + 0] = ls; red[(t >> 6) * 2 + 1] = lq; }
        __syncthreads();  // partials ready AND writes visible for next iter reads
        float tS = red[0] + red[2] + hS;
        float tQ = red[1] + red[3] + hQ;
        mu = tS * (1.0f / 1000.0f);
        var = tQ * (1.0f / 1000.0f) - mu * mu;
        inv = __builtin_amdgcn_rsqf(var + 1e-5f);
      }
    }
    // ---- write final interior from registers ----
    const int baseo = ((b * MM + gm0 + p) * NN + (gn0 + q0)) * KK + (gk0 + r0);
#pragma unroll
    for (int dq = 0; dq < 2; ++dq) {
      float2 ov; ov.x = a[dq][0]; ov.y = a[dq][1];
      *(float2*)(out + baseo + dq * KK) = ov;
    }
  }
}

extern "C" void kernel_launch(void* const* d_in, const int* in_sizes, int n_in,
                              void* d_out, int out_size, void* d_ws, size_t ws_size,
                              hipStream_t stream) {
  const float* weight = (const float*)d_in[0];
  const float* bias   = (const float*)d_in[1];
  const float* rscale = (const float*)d_in[2];
  const float* x      = (const float*)d_in[3];
  // d_in[4] = inner_iterations (8), d_in[5] = block_size (8): fixed by harness
  float* out = (float*)d_out;
  gridnet_kernel<<<dim3(16 * 16 * 16), dim3(128), 0, stream>>>(
      weight, bias, rscale, x, out);
}